// Round 11
// baseline (715.373 us; speedup 1.0000x reference)
//
#include <hip/hip_runtime.h>
#include <cstdint>

// SplineConv MeshEncoder: 3 layers, K=3 DIM=3 M=27, dims 3->64->64->64.
// R11: layer64 split into two barrier-free kernels through an HBM bf16 acc
// buffer (chunked to ws_size):
//   scatter_kernel: R8-proven per-node register Phase A, dump = 28 coalesced
//     128B global b16 stores (no LDS, no barriers, waves independent).
//   gemm_kernel: dense tall GEMM acc(cnt,1792)@wb(1792,64): per wave 16 nodes
//     x 64 outs; K-loop = 1 coalesced 1KB A-load + 4 L2-hot wb loads + 4 MFMA.
// Rationale: R8's fused block self-caps (barrier couples Phase A latency and
// Phase B's serial 56-deep wb chain; half the waves idle in B). HBM round
// trip ~60us/layer is cheaper than the structural stall.

typedef __attribute__((ext_vector_type(8))) short short8;
typedef __attribute__((ext_vector_type(4))) float floatx4;

__device__ inline short f2bf(float f) {
    union { float f; unsigned u; } x; x.f = f;
    unsigned r = x.u + 0x7FFF + ((x.u >> 16) & 1);   // round-to-nearest-even
    return (short)(r >> 16);
}

// ---------------- preprocessing (R10-proven) ----------------

__global__ void count_kernel(const int* __restrict__ ei, int* __restrict__ count, int E) {
    int e = blockIdx.x * blockDim.x + threadIdx.x;
    if (e < E) atomicAdd(&count[ei[E + e]], 1);
}

__global__ __launch_bounds__(1024) void scan_tile_kernel(const int* __restrict__ count,
                                                         int* __restrict__ row_ptr,
                                                         int* __restrict__ bsum, int N) {
    __shared__ int wsum[16];
    int tid = threadIdx.x, lane = tid & 63, wid = tid >> 6;
    int i = blockIdx.x * 1024 + tid;
    int v = (i < N) ? count[i] : 0;
    int incl = v;
#pragma unroll
    for (int off = 1; off < 64; off <<= 1) {
        int t = __shfl_up(incl, off, 64);
        if (lane >= off) incl += t;
    }
    if (lane == 63) wsum[wid] = incl;
    __syncthreads();
    if (tid < 16) {
        int w = wsum[tid];
#pragma unroll
        for (int off = 1; off < 16; off <<= 1) {
            int t = __shfl_up(w, off, 16);
            if ((tid & 15) >= off) w += t;
        }
        wsum[tid] = w;
    }
    __syncthreads();
    int waveoff = (wid > 0) ? wsum[wid - 1] : 0;
    if (i < N) row_ptr[i] = waveoff + incl - v;
    if (tid == 1023) bsum[blockIdx.x] = waveoff + incl;
}

__global__ __launch_bounds__(64) void scan_bsum_kernel(const int* __restrict__ bsum,
                                                       int* __restrict__ boff,
                                                       int* __restrict__ tot, int nb) {
    int tid = threadIdx.x;
    int v = (tid < nb) ? bsum[tid] : 0;
    int incl = v;
#pragma unroll
    for (int off = 1; off < 64; off <<= 1) {
        int t = __shfl_up(incl, off, 64);
        if (tid >= off) incl += t;
    }
    boff[tid] = incl - v;
    if (tid == 63) tot[0] = incl;
}

__global__ __launch_bounds__(1024) void scan_add_kernel(int* __restrict__ row_ptr,
                                                        const int* __restrict__ boff,
                                                        const int* __restrict__ tot,
                                                        int* __restrict__ cursor, int N) {
    int i = blockIdx.x * 1024 + threadIdx.x;
    if (i < N) {
        int r = row_ptr[i] + boff[blockIdx.x];
        row_ptr[i] = r;
        cursor[i] = r;
    }
    if (i == 0) row_ptr[N] = tot[0];
}

// Per edge: meta = src | base<<24, weights pre-scaled by 1/deg, scattered to
// dst-sorted position (two float4 stores). kidx = base + {0,1,3,4,9,10,12,13}[c].
__global__ void basis_sort_kernel(const int* __restrict__ ei, const float* __restrict__ attr,
                                  const int* __restrict__ count, int* __restrict__ cursor,
                                  int* __restrict__ s_meta, float* __restrict__ s_w, int E) {
    int e = blockIdx.x * blockDim.x + threadIdx.x;
    if (e >= E) return;
    int src = ei[e];
    int dst = ei[E + e];
    float f[3]; int i0[3];
#pragma unroll
    for (int d = 0; d < 3; d++) {
        float pos = attr[e * 3 + d] * 2.0f;          // K-1 = 2
        float fl = floorf(pos);
        fl = fminf(fmaxf(fl, 0.0f), 1.0f);           // clip to [0, K-2]
        i0[d] = (int)fl;
        f[d] = pos - fl;
    }
    int base = i0[0] + 3 * i0[1] + 9 * i0[2];        // in {0,1,3,4,9,10,12,13}
    float invd = 1.0f / fmaxf((float)count[dst], 1.0f);
    int p = atomicAdd(&cursor[dst], 1);
    s_meta[p] = src | (base << 24);
    float w[8];
#pragma unroll
    for (int c = 0; c < 8; c++) {
        float ww = 1.0f;
#pragma unroll
        for (int d = 0; d < 3; d++) {
            int off = (c >> d) & 1;
            ww *= off ? f[d] : (1.0f - f[d]);
        }
        w[c] = ww * invd;
    }
    floatx4 w03 = {w[0], w[1], w[2], w[3]};
    floatx4 w47 = {w[4], w[5], w[6], w[7]};
    *(floatx4*)(s_w + (size_t)p * 8) = w03;
    *(floatx4*)(s_w + (size_t)p * 8 + 4) = w47;
}

// Pre-swizzle [W(1728,64); Wr(64,64)] into bf16 MFMA B-frag order (R1-proven).
__global__ void build_wb(const float* __restrict__ W, const float* __restrict__ Wr,
                         unsigned short* __restrict__ wb) {
    int idx = blockIdx.x * blockDim.x + threadIdx.x;   // [0, 4*56*64)
    if (idx >= 4 * 56 * 64) return;
    int l = idx & 63;
    int c = (idx >> 6) % 56;
    int t = idx / (56 * 64);
    int q = l >> 4, o = t * 16 + (l & 15);
    short8 out;
#pragma unroll
    for (int j = 0; j < 8; j++) {
        int k = c * 32 + q * 8 + j;
        float v = (k < 1728) ? W[(size_t)k * 64 + o] : Wr[(size_t)(k - 1728) * 64 + o];
        out[j] = f2bf(v);
    }
    *(short8*)(wb + (size_t)idx * 8) = out;
}

// ---------------- layer 0 (CIN=3), R10-proven ----------------
__global__ __launch_bounds__(256) void layer0_kernel(
    const float* __restrict__ x, const float* __restrict__ W0,
    const float* __restrict__ Wr, const float* __restrict__ bias,
    const int* __restrict__ row_ptr, const int* __restrict__ s_meta,
    const float* __restrict__ s_w, float* __restrict__ h_out, int N) {
    constexpr int NPB = 32, KT = 84;
    __shared__ __align__(16) float acc[NPB * KT];
    int tid = threadIdx.x, lane = tid & 63, wv = tid >> 6;
    int n0 = blockIdx.x * NPB;
    for (int k = tid; k < NPB * KT; k += 256) acc[k] = 0.0f;
    __syncthreads();

    int c = lane / 3, i = lane - c * 3;
    int cc = (lane < 24) ? c : 0;                     // clamp for safe loads
    int coff = (c & 1) + 3 * ((c >> 1) & 1) + 9 * (c >> 2);   // corner offset
    bool act = (lane < 24);

#define BATCH0(SZ) do { \
    int metas[SZ]; float ws_[SZ], xs_[SZ]; \
    _Pragma("unroll") for (int j = 0; j < SZ; j++) metas[j] = s_meta[e + j]; \
    _Pragma("unroll") for (int j = 0; j < SZ; j++) \
        ws_[j] = s_w[(size_t)(e + j) * 8 + cc]; \
    _Pragma("unroll") for (int j = 0; j < SZ; j++) \
        xs_[j] = x[(size_t)(metas[j] & 0xFFFFFF) * 3 + i]; \
    _Pragma("unroll") for (int j = 0; j < SZ; j++) { \
        int kidx = ((metas[j] >> 24) & 0xF) + coff; \
        if (act) acc[g * KT + kidx * 3 + i] += ws_[j] * xs_[j]; \
    } \
    e += SZ; \
} while (0)

    for (int g2 = 0; g2 < 8; g2++) {
        int g = wv * 8 + g2;
        int n = n0 + g;
        if (n >= N) continue;
        if (lane < 3) acc[g * KT + 81 + lane] = x[(size_t)n * 3 + lane];
        int rs = row_ptr[n], re = row_ptr[n + 1];
        int e = rs;
        while (e + 8 <= re) BATCH0(8);
        if (e + 4 <= re) BATCH0(4);
        for (; e < re; e++) {
            int meta = s_meta[e];
            if (act) {
                int src = meta & 0xFFFFFF;
                int kidx = ((meta >> 24) & 0xF) + coff;
                float w = s_w[(size_t)e * 8 + c];
                float xj = x[(size_t)src * 3 + i];
                acc[g * KT + kidx * 3 + i] += w * xj;
            }
        }
    }
#undef BATCH0
    __syncthreads();

    int o = lane;
    float wreg[KT];
#pragma unroll
    for (int k = 0; k < KT; k++)
        wreg[k] = (k < 81) ? W0[k * 64 + o] : Wr[(k - 81) * 64 + o];
    float bv = bias[o];
    for (int g = wv; g < NPB; g += 4) {
        int n = n0 + g;
        if (n >= N) break;
        float s = bv;
#pragma unroll
        for (int k4 = 0; k4 < KT; k4 += 4) {
            floatx4 a = *(const floatx4*)&acc[g * KT + k4];
            s += a.x * wreg[k4] + a.y * wreg[k4 + 1] + a.z * wreg[k4 + 2] + a.w * wreg[k4 + 3];
        }
        h_out[(size_t)n * 64 + o] = fmaxf(s, 0.0f);
    }
}

// ---------------- 64-ch layers, stage 1: scatter (no LDS, no barriers) --------
__global__ __launch_bounds__(256) void scatter_kernel(
    const float* __restrict__ h_in, const int* __restrict__ row_ptr,
    const int* __restrict__ s_meta, const float* __restrict__ s_w,
    unsigned short* __restrict__ accg, int cbase, int cnt) {
    int lane = threadIdx.x & 63;
    int wvu = __builtin_amdgcn_readfirstlane(threadIdx.x >> 6);   // 0..3
    int ln = blockIdx.x * 4 + wvu;                                // local node
    if (ln >= cnt) return;
    int n = cbase + ln;
    unsigned short* arow = accg + (size_t)ln * 1792;

#define EDGE_FMA(EIDX, XJ) do { \
    const float* wp = s_w + (size_t)(EIDX) * 8; \
    float w0 = wp[0], w1 = wp[1], w2 = wp[2], w3 = wp[3]; \
    float w4 = wp[4], w5 = wp[5], w6 = wp[6], w7 = wp[7]; \
    float xj = (XJ); \
    switch (bases) { \
    case 0:  acc[0]+=w0*xj;  acc[1]+=w1*xj;  acc[3]+=w2*xj;  acc[4]+=w3*xj; \
             acc[9]+=w4*xj;  acc[10]+=w5*xj; acc[12]+=w6*xj; acc[13]+=w7*xj; break; \
    case 1:  acc[1]+=w0*xj;  acc[2]+=w1*xj;  acc[4]+=w2*xj;  acc[5]+=w3*xj; \
             acc[10]+=w4*xj; acc[11]+=w5*xj; acc[13]+=w6*xj; acc[14]+=w7*xj; break; \
    case 3:  acc[3]+=w0*xj;  acc[4]+=w1*xj;  acc[6]+=w2*xj;  acc[7]+=w3*xj; \
             acc[12]+=w4*xj; acc[13]+=w5*xj; acc[15]+=w6*xj; acc[16]+=w7*xj; break; \
    case 4:  acc[4]+=w0*xj;  acc[5]+=w1*xj;  acc[7]+=w2*xj;  acc[8]+=w3*xj; \
             acc[13]+=w4*xj; acc[14]+=w5*xj; acc[16]+=w6*xj; acc[17]+=w7*xj; break; \
    case 9:  acc[9]+=w0*xj;  acc[10]+=w1*xj; acc[12]+=w2*xj; acc[13]+=w3*xj; \
             acc[18]+=w4*xj; acc[19]+=w5*xj; acc[21]+=w6*xj; acc[22]+=w7*xj; break; \
    case 10: acc[10]+=w0*xj; acc[11]+=w1*xj; acc[13]+=w2*xj; acc[14]+=w3*xj; \
             acc[19]+=w4*xj; acc[20]+=w5*xj; acc[22]+=w6*xj; acc[23]+=w7*xj; break; \
    case 12: acc[12]+=w0*xj; acc[13]+=w1*xj; acc[15]+=w2*xj; acc[16]+=w3*xj; \
             acc[21]+=w4*xj; acc[22]+=w5*xj; acc[24]+=w6*xj; acc[25]+=w7*xj; break; \
    default: acc[13]+=w0*xj; acc[14]+=w1*xj; acc[16]+=w2*xj; acc[17]+=w3*xj; \
             acc[22]+=w4*xj; acc[23]+=w5*xj; acc[25]+=w6*xj; acc[26]+=w7*xj; break; } \
} while (0)

#define BATCH(SZ) do { \
    int metas[SZ]; float xjs[SZ]; \
    _Pragma("unroll") for (int j = 0; j < SZ; j++) metas[j] = s_meta[e + j]; \
    _Pragma("unroll") for (int j = 0; j < SZ; j++) \
        xjs[j] = h_in[(size_t)(metas[j] & 0xFFFFFF) * 64 + lane]; \
    _Pragma("unroll") for (int j = 0; j < SZ; j++) { \
        int bases = (metas[j] >> 24) & 0xF; \
        EDGE_FMA(e + j, xjs[j]); \
    } \
    e += SZ; \
} while (0)

    float acc[27];
#pragma unroll
    for (int m = 0; m < 27; m++) acc[m] = 0.0f;
    int rs = row_ptr[n], re = row_ptr[n + 1];
    int e = rs;
    while (e + 16 <= re) BATCH(16);
    if (e + 8 <= re) BATCH(8);
    if (e + 4 <= re) BATCH(4);
    for (; e < re; e++) {                     // <=3 remainder
        int meta = s_meta[e];
        float xjr = h_in[(size_t)(meta & 0xFFFFFF) * 64 + lane];
        int bases = (meta >> 24) & 0xF;
        EDGE_FMA(e, xjr);
    }
#undef BATCH
#undef EDGE_FMA
    // dump: 28 coalesced 128B b16 stores (k = m*64 + lane; root at 1728+lane)
#pragma unroll
    for (int m = 0; m < 27; m++)
        arow[m * 64 + lane] = (unsigned short)f2bf(acc[m]);
    arow[1728 + lane] = (unsigned short)f2bf(h_in[(size_t)n * 64 + lane]);
}

// ---------------- 64-ch layers, stage 2: dense tall GEMM ----------------
// Per wave: 16 nodes x 64 outs. K-loop: 1 coalesced 1KB A-load + 4 wb loads
// (L2-hot, 229KB) + 4 MFMA. No LDS, no barriers. C-layout R8-proven.
__global__ __launch_bounds__(256) void gemm_kernel(
    const unsigned short* __restrict__ accg, const unsigned short* __restrict__ wb,
    const float* __restrict__ bias, float* __restrict__ h_out,
    int cbase, int cnt16, int N) {
    int lane = threadIdx.x & 63, wv = threadIdx.x >> 6;
    int n0l = (blockIdx.x * 4 + wv) * 16;
    if (n0l >= cnt16) return;
    const unsigned short* ap = accg + (size_t)(n0l + (lane & 15)) * 1792 + ((lane >> 4) * 8);
    const unsigned short* wbl = wb + (size_t)lane * 8;
    floatx4 facc[4];
#pragma unroll
    for (int t = 0; t < 4; t++) facc[t] = (floatx4){0.0f, 0.0f, 0.0f, 0.0f};
#pragma unroll 2
    for (int c = 0; c < 56; c++) {
        short8 af = *(const short8*)(ap + (size_t)c * 32);
#pragma unroll
        for (int t = 0; t < 4; t++) {
            short8 bf = *(const short8*)(wbl + ((size_t)(t * 56 + c) * 64) * 8);
            facc[t] = __builtin_amdgcn_mfma_f32_16x16x32_bf16(af, bf, facc[t], 0, 0, 0);
        }
    }
#pragma unroll
    for (int t = 0; t < 4; t++) {
        int o = t * 16 + (lane & 15);
        float bv = bias[o];
#pragma unroll
        for (int r = 0; r < 4; r++) {
            int m = (lane >> 4) * 4 + r;
            int n = cbase + n0l + m;
            if (n < N) h_out[(size_t)n * 64 + o] = fmaxf(facc[t][r] + bv, 0.0f);
        }
    }
}

extern "C" void kernel_launch(void* const* d_in, const int* in_sizes, int n_in,
                              void* d_out, int out_size, void* d_ws, size_t ws_size,
                              hipStream_t stream) {
    (void)n_in; (void)out_size;
    const float* x    = (const float*)d_in[0];
    const int*   ei   = (const int*)d_in[1];
    const float* attr = (const float*)d_in[2];
    const float* W0 = (const float*)d_in[3];
    const float* R0 = (const float*)d_in[4];
    const float* B0 = (const float*)d_in[5];
    const float* W1 = (const float*)d_in[6];
    const float* R1 = (const float*)d_in[7];
    const float* B1 = (const float*)d_in[8];
    const float* W2 = (const float*)d_in[9];
    const float* R2 = (const float*)d_in[10];
    const float* B2 = (const float*)d_in[11];
    const int N = in_sizes[0] / 3;
    const int E = in_sizes[1] / 2;

    char* ws = (char*)d_ws;
    size_t off = 0;
    auto alloc = [&](size_t bytes) {
        size_t cur = off;
        off = (off + bytes + 255) & ~(size_t)255;
        return cur;
    };
    int* row_ptr = (int*)(ws + alloc((size_t)(N + 1) * 4));
    int* count   = (int*)(ws + alloc((size_t)N * 4));
    int* cursor  = (int*)(ws + alloc((size_t)N * 4));
    int* bsum    = (int*)(ws + alloc(64 * 4));
    int* boff    = (int*)(ws + alloc(64 * 4));
    int* tot     = (int*)(ws + alloc(4));
    int* s_meta  = (int*)(ws + alloc((size_t)E * 4));
    float* s_w   = (float*)(ws + alloc((size_t)E * 8 * 4));
    float* h_a   = (float*)(ws + alloc((size_t)N * 64 * 4));
    float* h_b   = (float*)(ws + alloc((size_t)N * 64 * 4));
    unsigned short* wb1 = (unsigned short*)(ws + alloc((size_t)4 * 56 * 64 * 8 * 2));
    unsigned short* wb2 = (unsigned short*)(ws + alloc((size_t)4 * 56 * 64 * 8 * 2));

    // acc buffer: chunked to whatever ws space remains (deterministic in
    // ws_size -> same work every call).
    unsigned short* accg = (unsigned short*)(ws + off);
    size_t avail = (ws_size > off) ? ws_size - off : 0;
    const size_t rowB = 1792 * 2;
    long rows = (long)(avail / rowB) - 16;            // -16: pad rows for gemm tiles
    if (rows < 16) rows = 16;
    rows &= ~15L;
    long npad = (long)((N + 15) & ~15);
    int npc = (int)((rows < npad) ? rows : npad);     // nodes per chunk (mult of 16)
    int nch = (int)((N + npc - 1) / npc);

    int nb = (N + 1023) / 1024;   // 49 <= 64

    hipMemsetAsync(count, 0, (size_t)N * 4, stream);
    count_kernel<<<(E + 255) / 256, 256, 0, stream>>>(ei, count, E);
    scan_tile_kernel<<<nb, 1024, 0, stream>>>(count, row_ptr, bsum, N);
    scan_bsum_kernel<<<1, 64, 0, stream>>>(bsum, boff, tot, nb);
    scan_add_kernel<<<nb, 1024, 0, stream>>>(row_ptr, boff, tot, cursor, N);
    basis_sort_kernel<<<(E + 255) / 256, 256, 0, stream>>>(ei, attr, count, cursor,
                                                           s_meta, s_w, E);
    build_wb<<<(4 * 56 * 64 + 255) / 256, 256, 0, stream>>>(W1, R1, wb1);
    build_wb<<<(4 * 56 * 64 + 255) / 256, 256, 0, stream>>>(W2, R2, wb2);

    layer0_kernel<<<(N + 31) / 32, 256, 0, stream>>>(x, W0, R0, B0, row_ptr,
                                                     s_meta, s_w, h_a, N);

    auto run64 = [&](const float* hin, const unsigned short* wbp, const float* bp,
                     float* hout) {
        for (int ci = 0; ci < nch; ci++) {
            int cb = ci * npc;
            int cnt = (N - cb < npc) ? (N - cb) : npc;
            int cnt16 = (cnt + 15) & ~15;
            scatter_kernel<<<(cnt + 3) / 4, 256, 0, stream>>>(hin, row_ptr, s_meta,
                                                              s_w, accg, cb, cnt);
            gemm_kernel<<<(cnt16 / 16 + 3) / 4, 256, 0, stream>>>(accg, wbp, bp, hout,
                                                                  cb, cnt16, N);
        }
    };
    run64(h_a, wb1, B1, h_b);
    run64(h_b, wb2, B2, (float*)d_out);
}

// Round 12
// 680.835 us; speedup vs baseline: 1.0507x; 1.0507x over previous
//
#include <hip/hip_runtime.h>
#include <cstdint>

// SplineConv MeshEncoder: 3 layers, K=3 DIM=3 M=27, dims 3->64->64->64.
// R12 = R10 (best: fused layer64, LDS acc — avoids R11's 179MB HBM round
// trip) with Phase B upgraded: ALL 8 waves, 2-way split-K (wave w: tile w&3,
// K-half w>>2, 28 chunks) + LDS reduction reusing accb. A-rows stay lane&7
// duplicated -> broadcast reads, conflict-free (R9's 16-distinct-row version
// hit 2.8e6 conflicts; this keeps 0). Serial wb chain 56 -> 28, no idle waves.

typedef __attribute__((ext_vector_type(8))) short short8;
typedef __attribute__((ext_vector_type(4))) float floatx4;

__device__ inline short f2bf(float f) {
    union { float f; unsigned u; } x; x.f = f;
    unsigned r = x.u + 0x7FFF + ((x.u >> 16) & 1);   // round-to-nearest-even
    return (short)(r >> 16);
}

// ---------------- preprocessing (R10-proven) ----------------

__global__ void count_kernel(const int* __restrict__ ei, int* __restrict__ count, int E) {
    int e = blockIdx.x * blockDim.x + threadIdx.x;
    if (e < E) atomicAdd(&count[ei[E + e]], 1);
}

__global__ __launch_bounds__(1024) void scan_tile_kernel(const int* __restrict__ count,
                                                         int* __restrict__ row_ptr,
                                                         int* __restrict__ bsum, int N) {
    __shared__ int wsum[16];
    int tid = threadIdx.x, lane = tid & 63, wid = tid >> 6;
    int i = blockIdx.x * 1024 + tid;
    int v = (i < N) ? count[i] : 0;
    int incl = v;
#pragma unroll
    for (int off = 1; off < 64; off <<= 1) {
        int t = __shfl_up(incl, off, 64);
        if (lane >= off) incl += t;
    }
    if (lane == 63) wsum[wid] = incl;
    __syncthreads();
    if (tid < 16) {
        int w = wsum[tid];
#pragma unroll
        for (int off = 1; off < 16; off <<= 1) {
            int t = __shfl_up(w, off, 16);
            if ((tid & 15) >= off) w += t;
        }
        wsum[tid] = w;
    }
    __syncthreads();
    int waveoff = (wid > 0) ? wsum[wid - 1] : 0;
    if (i < N) row_ptr[i] = waveoff + incl - v;
    if (tid == 1023) bsum[blockIdx.x] = waveoff + incl;
}

__global__ __launch_bounds__(64) void scan_bsum_kernel(const int* __restrict__ bsum,
                                                       int* __restrict__ boff,
                                                       int* __restrict__ tot, int nb) {
    int tid = threadIdx.x;
    int v = (tid < nb) ? bsum[tid] : 0;
    int incl = v;
#pragma unroll
    for (int off = 1; off < 64; off <<= 1) {
        int t = __shfl_up(incl, off, 64);
        if (tid >= off) incl += t;
    }
    boff[tid] = incl - v;
    if (tid == 63) tot[0] = incl;
}

__global__ __launch_bounds__(1024) void scan_add_kernel(int* __restrict__ row_ptr,
                                                        const int* __restrict__ boff,
                                                        const int* __restrict__ tot,
                                                        int* __restrict__ cursor, int N) {
    int i = blockIdx.x * 1024 + threadIdx.x;
    if (i < N) {
        int r = row_ptr[i] + boff[blockIdx.x];
        row_ptr[i] = r;
        cursor[i] = r;
    }
    if (i == 0) row_ptr[N] = tot[0];
}

// Per edge: meta = src | base<<24, weights pre-scaled by 1/deg, scattered to
// dst-sorted position (two float4 stores). kidx = base + {0,1,3,4,9,10,12,13}[c].
__global__ void basis_sort_kernel(const int* __restrict__ ei, const float* __restrict__ attr,
                                  const int* __restrict__ count, int* __restrict__ cursor,
                                  int* __restrict__ s_meta, float* __restrict__ s_w, int E) {
    int e = blockIdx.x * blockDim.x + threadIdx.x;
    if (e >= E) return;
    int src = ei[e];
    int dst = ei[E + e];
    float f[3]; int i0[3];
#pragma unroll
    for (int d = 0; d < 3; d++) {
        float pos = attr[e * 3 + d] * 2.0f;          // K-1 = 2
        float fl = floorf(pos);
        fl = fminf(fmaxf(fl, 0.0f), 1.0f);           // clip to [0, K-2]
        i0[d] = (int)fl;
        f[d] = pos - fl;
    }
    int base = i0[0] + 3 * i0[1] + 9 * i0[2];        // in {0,1,3,4,9,10,12,13}
    float invd = 1.0f / fmaxf((float)count[dst], 1.0f);
    int p = atomicAdd(&cursor[dst], 1);
    s_meta[p] = src | (base << 24);
    float w[8];
#pragma unroll
    for (int c = 0; c < 8; c++) {
        float ww = 1.0f;
#pragma unroll
        for (int d = 0; d < 3; d++) {
            int off = (c >> d) & 1;
            ww *= off ? f[d] : (1.0f - f[d]);
        }
        w[c] = ww * invd;
    }
    floatx4 w03 = {w[0], w[1], w[2], w[3]};
    floatx4 w47 = {w[4], w[5], w[6], w[7]};
    *(floatx4*)(s_w + (size_t)p * 8) = w03;
    *(floatx4*)(s_w + (size_t)p * 8 + 4) = w47;
}

// Pre-swizzle [W(1728,64); Wr(64,64)] into bf16 MFMA B-frag order (R1-proven).
__global__ void build_wb(const float* __restrict__ W, const float* __restrict__ Wr,
                         unsigned short* __restrict__ wb) {
    int idx = blockIdx.x * blockDim.x + threadIdx.x;   // [0, 4*56*64)
    if (idx >= 4 * 56 * 64) return;
    int l = idx & 63;
    int c = (idx >> 6) % 56;
    int t = idx / (56 * 64);
    int q = l >> 4, o = t * 16 + (l & 15);
    short8 out;
#pragma unroll
    for (int j = 0; j < 8; j++) {
        int k = c * 32 + q * 8 + j;
        float v = (k < 1728) ? W[(size_t)k * 64 + o] : Wr[(size_t)(k - 1728) * 64 + o];
        out[j] = f2bf(v);
    }
    *(short8*)(wb + (size_t)idx * 8) = out;
}

// ---------------- layer 0 (CIN=3), R10-proven ----------------
__global__ __launch_bounds__(256) void layer0_kernel(
    const float* __restrict__ x, const float* __restrict__ W0,
    const float* __restrict__ Wr, const float* __restrict__ bias,
    const int* __restrict__ row_ptr, const int* __restrict__ s_meta,
    const float* __restrict__ s_w, float* __restrict__ h_out, int N) {
    constexpr int NPB = 32, KT = 84;
    __shared__ __align__(16) float acc[NPB * KT];
    int tid = threadIdx.x, lane = tid & 63, wv = tid >> 6;
    int n0 = blockIdx.x * NPB;
    for (int k = tid; k < NPB * KT; k += 256) acc[k] = 0.0f;
    __syncthreads();

    int c = lane / 3, i = lane - c * 3;
    int cc = (lane < 24) ? c : 0;                     // clamp for safe loads
    int coff = (c & 1) + 3 * ((c >> 1) & 1) + 9 * (c >> 2);   // corner offset
    bool act = (lane < 24);

#define BATCH0(SZ) do { \
    int metas[SZ]; float ws_[SZ], xs_[SZ]; \
    _Pragma("unroll") for (int j = 0; j < SZ; j++) metas[j] = s_meta[e + j]; \
    _Pragma("unroll") for (int j = 0; j < SZ; j++) \
        ws_[j] = s_w[(size_t)(e + j) * 8 + cc]; \
    _Pragma("unroll") for (int j = 0; j < SZ; j++) \
        xs_[j] = x[(size_t)(metas[j] & 0xFFFFFF) * 3 + i]; \
    _Pragma("unroll") for (int j = 0; j < SZ; j++) { \
        int kidx = ((metas[j] >> 24) & 0xF) + coff; \
        if (act) acc[g * KT + kidx * 3 + i] += ws_[j] * xs_[j]; \
    } \
    e += SZ; \
} while (0)

    for (int g2 = 0; g2 < 8; g2++) {
        int g = wv * 8 + g2;
        int n = n0 + g;
        if (n >= N) continue;
        if (lane < 3) acc[g * KT + 81 + lane] = x[(size_t)n * 3 + lane];
        int rs = row_ptr[n], re = row_ptr[n + 1];
        int e = rs;
        while (e + 8 <= re) BATCH0(8);
        if (e + 4 <= re) BATCH0(4);
        for (; e < re; e++) {
            int meta = s_meta[e];
            if (act) {
                int src = meta & 0xFFFFFF;
                int kidx = ((meta >> 24) & 0xF) + coff;
                float w = s_w[(size_t)e * 8 + c];
                float xj = x[(size_t)src * 3 + i];
                acc[g * KT + kidx * 3 + i] += w * xj;
            }
        }
    }
#undef BATCH0
    __syncthreads();

    int o = lane;
    float wreg[KT];
#pragma unroll
    for (int k = 0; k < KT; k++)
        wreg[k] = (k < 81) ? W0[k * 64 + o] : Wr[(k - 81) * 64 + o];
    float bv = bias[o];
    for (int g = wv; g < NPB; g += 4) {
        int n = n0 + g;
        if (n >= N) break;
        float s = bv;
#pragma unroll
        for (int k4 = 0; k4 < KT; k4 += 4) {
            floatx4 a = *(const floatx4*)&acc[g * KT + k4];
            s += a.x * wreg[k4] + a.y * wreg[k4 + 1] + a.z * wreg[k4 + 2] + a.w * wreg[k4 + 3];
        }
        h_out[(size_t)n * 64 + o] = fmaxf(s, 0.0f);
    }
}

// ---------------- 64-ch layers: 1 node/wave Phase A + all-wave split-K Phase B ----
__global__ __launch_bounds__(512) void layer64_kernel(
    const float* __restrict__ h_in, const unsigned short* __restrict__ wb,
    const float* __restrict__ bias, const int* __restrict__ row_ptr,
    const int* __restrict__ s_meta, const float* __restrict__ s_w,
    float* __restrict__ h_out, int N) {
    constexpr int NPB = 8;
    constexpr int STR = 1808;            // shorts; dword-stride 904 = even bank spread
    __shared__ __align__(16) unsigned short accb[NPB * STR];   // 28,928 B
    int tid = threadIdx.x, lane = tid & 63;
    int wvu = __builtin_amdgcn_readfirstlane(tid >> 6);   // uniform wave id 0..7
    int n0 = blockIdx.x * NPB;

#define EDGE_FMA(EIDX, XJ) do { \
    const float* wp = s_w + (size_t)(EIDX) * 8; \
    float w0 = wp[0], w1 = wp[1], w2 = wp[2], w3 = wp[3]; \
    float w4 = wp[4], w5 = wp[5], w6 = wp[6], w7 = wp[7]; \
    float xj = (XJ); \
    switch (bases) { \
    case 0:  acc[0]+=w0*xj;  acc[1]+=w1*xj;  acc[3]+=w2*xj;  acc[4]+=w3*xj; \
             acc[9]+=w4*xj;  acc[10]+=w5*xj; acc[12]+=w6*xj; acc[13]+=w7*xj; break; \
    case 1:  acc[1]+=w0*xj;  acc[2]+=w1*xj;  acc[4]+=w2*xj;  acc[5]+=w3*xj; \
             acc[10]+=w4*xj; acc[11]+=w5*xj; acc[13]+=w6*xj; acc[14]+=w7*xj; break; \
    case 3:  acc[3]+=w0*xj;  acc[4]+=w1*xj;  acc[6]+=w2*xj;  acc[7]+=w3*xj; \
             acc[12]+=w4*xj; acc[13]+=w5*xj; acc[15]+=w6*xj; acc[16]+=w7*xj; break; \
    case 4:  acc[4]+=w0*xj;  acc[5]+=w1*xj;  acc[7]+=w2*xj;  acc[8]+=w3*xj; \
             acc[13]+=w4*xj; acc[14]+=w5*xj; acc[16]+=w6*xj; acc[17]+=w7*xj; break; \
    case 9:  acc[9]+=w0*xj;  acc[10]+=w1*xj; acc[12]+=w2*xj; acc[13]+=w3*xj; \
             acc[18]+=w4*xj; acc[19]+=w5*xj; acc[21]+=w6*xj; acc[22]+=w7*xj; break; \
    case 10: acc[10]+=w0*xj; acc[11]+=w1*xj; acc[13]+=w2*xj; acc[14]+=w3*xj; \
             acc[19]+=w4*xj; acc[20]+=w5*xj; acc[22]+=w6*xj; acc[23]+=w7*xj; break; \
    case 12: acc[12]+=w0*xj; acc[13]+=w1*xj; acc[15]+=w2*xj; acc[16]+=w3*xj; \
             acc[21]+=w4*xj; acc[22]+=w5*xj; acc[24]+=w6*xj; acc[25]+=w7*xj; break; \
    default: acc[13]+=w0*xj; acc[14]+=w1*xj; acc[16]+=w2*xj; acc[17]+=w3*xj; \
             acc[22]+=w4*xj; acc[23]+=w5*xj; acc[25]+=w6*xj; acc[26]+=w7*xj; break; } \
} while (0)

#define BATCH(SZ) do { \
    int metas[SZ]; float xjs[SZ]; \
    _Pragma("unroll") for (int j = 0; j < SZ; j++) metas[j] = s_meta[e + j]; \
    _Pragma("unroll") for (int j = 0; j < SZ; j++) \
        xjs[j] = h_in[(size_t)(metas[j] & 0xFFFFFF) * 64 + lane]; \
    _Pragma("unroll") for (int j = 0; j < SZ; j++) { \
        int bases = (metas[j] >> 24) & 0xF; \
        EDGE_FMA(e + j, xjs[j]); \
    } \
    e += SZ; \
} while (0)

    // Phase A (R8-proven): wave wvu owns node row wvu. lane = channel.
    {
        int r = wvu;
        int n = n0 + r;
        unsigned short* arowb = &accb[r * STR];
        if (n >= N) {   // tail hygiene: zero the row so MFMA sees no stale LDS
            for (int k = lane; k < 1792; k += 64) arowb[k] = 0;
        } else {
            float acc[27];
#pragma unroll
            for (int m = 0; m < 27; m++) acc[m] = 0.0f;
            int rs = row_ptr[n], re = row_ptr[n + 1];
            int e = rs;
            while (e + 16 <= re) BATCH(16);
            if (e + 8 <= re) BATCH(8);
            if (e + 4 <= re) BATCH(4);
            for (; e < re; e++) {                     // <=3 remainder
                int meta = s_meta[e];
                float xjr = h_in[(size_t)(meta & 0xFFFFFF) * 64 + lane];
                int bases = (meta >> 24) & 0xF;
                EDGE_FMA(e, xjr);
            }
#pragma unroll
            for (int m = 0; m < 27; m++)
                arowb[m * 64 + lane] = (unsigned short)f2bf(acc[m]);
            arowb[1728 + lane] = (unsigned short)f2bf(h_in[(size_t)n * 64 + lane]);
        }
    }
#undef BATCH
#undef EDGE_FMA
    __syncthreads();

    // Phase B: all 8 waves, 2-way split-K. Wave w: tile t=w&3 (16 out chans),
    // K-half hf=w>>2 (28 of 56 chunks). A rows lane&7-duplicated = broadcast
    // reads (conflict-free). Then LDS reduce (reuse accb) + store by waves 0-3.
    {
        int t = wvu & 3;
        int hf = wvu >> 2;
        const unsigned short* ap = accb + (lane & 7) * STR + ((lane >> 4) * 8);
        floatx4 facc = {0.0f, 0.0f, 0.0f, 0.0f};
        const unsigned short* wbp = wb + ((size_t)(t * 56) * 64 + lane) * 8;
#pragma unroll
        for (int ci = 0; ci < 28; ci++) {
            int c = hf * 28 + ci;
            short8 af = *(const short8*)(ap + c * 32);
            short8 bfr = *(const short8*)(wbp + (size_t)c * 64 * 8);
            facc = __builtin_amdgcn_mfma_f32_16x16x32_bf16(af, bfr, facc, 0, 0, 0);
        }
        __syncthreads();               // all MFMA reads of accb complete
        float* pf = (float*)accb;      // 8 waves x 256 floats = 8KB (fits)
#pragma unroll
        for (int r = 0; r < 4; r++) pf[wvu * 256 + r * 64 + lane] = facc[r];
        __syncthreads();
        if (wvu < 4) {
            int o = t * 16 + (lane & 15);
            float bv = bias[o];
#pragma unroll
            for (int r = 0; r < 4; r++) {
                int m = (lane >> 4) * 4 + r;
                if (m < 8) {
                    int n = n0 + m;
                    if (n < N) {
                        float s = pf[t * 256 + r * 64 + lane]
                                + pf[(t + 4) * 256 + r * 64 + lane];
                        h_out[(size_t)n * 64 + o] = fmaxf(s + bv, 0.0f);
                    }
                }
            }
        }
    }
}

extern "C" void kernel_launch(void* const* d_in, const int* in_sizes, int n_in,
                              void* d_out, int out_size, void* d_ws, size_t ws_size,
                              hipStream_t stream) {
    (void)n_in; (void)out_size; (void)ws_size;
    const float* x    = (const float*)d_in[0];
    const int*   ei   = (const int*)d_in[1];
    const float* attr = (const float*)d_in[2];
    const float* W0 = (const float*)d_in[3];
    const float* R0 = (const float*)d_in[4];
    const float* B0 = (const float*)d_in[5];
    const float* W1 = (const float*)d_in[6];
    const float* R1 = (const float*)d_in[7];
    const float* B1 = (const float*)d_in[8];
    const float* W2 = (const float*)d_in[9];
    const float* R2 = (const float*)d_in[10];
    const float* B2 = (const float*)d_in[11];
    const int N = in_sizes[0] / 3;
    const int E = in_sizes[1] / 2;

    char* ws = (char*)d_ws;
    size_t off = 0;
    auto alloc = [&](size_t bytes) {
        size_t cur = off;
        off = (off + bytes + 255) & ~(size_t)255;
        return cur;
    };
    int* row_ptr = (int*)(ws + alloc((size_t)(N + 1) * 4));
    int* count   = (int*)(ws + alloc((size_t)N * 4));
    int* cursor  = (int*)(ws + alloc((size_t)N * 4));
    int* bsum    = (int*)(ws + alloc(64 * 4));
    int* boff    = (int*)(ws + alloc(64 * 4));
    int* tot     = (int*)(ws + alloc(4));
    int* s_meta  = (int*)(ws + alloc((size_t)E * 4));
    float* s_w   = (float*)(ws + alloc((size_t)E * 8 * 4));
    float* h_a   = (float*)(ws + alloc((size_t)N * 64 * 4));
    float* h_b   = (float*)(ws + alloc((size_t)N * 64 * 4));
    unsigned short* wb1 = (unsigned short*)(ws + alloc((size_t)4 * 56 * 64 * 8 * 2));
    unsigned short* wb2 = (unsigned short*)(ws + alloc((size_t)4 * 56 * 64 * 8 * 2));

    int nb = (N + 1023) / 1024;   // 49 <= 64

    hipMemsetAsync(count, 0, (size_t)N * 4, stream);
    count_kernel<<<(E + 255) / 256, 256, 0, stream>>>(ei, count, E);
    scan_tile_kernel<<<nb, 1024, 0, stream>>>(count, row_ptr, bsum, N);
    scan_bsum_kernel<<<1, 64, 0, stream>>>(bsum, boff, tot, nb);
    scan_add_kernel<<<nb, 1024, 0, stream>>>(row_ptr, boff, tot, cursor, N);
    basis_sort_kernel<<<(E + 255) / 256, 256, 0, stream>>>(ei, attr, count, cursor,
                                                           s_meta, s_w, E);
    build_wb<<<(4 * 56 * 64 + 255) / 256, 256, 0, stream>>>(W1, R1, wb1);
    build_wb<<<(4 * 56 * 64 + 255) / 256, 256, 0, stream>>>(W2, R2, wb2);

    layer0_kernel<<<(N + 31) / 32, 256, 0, stream>>>(x, W0, R0, B0, row_ptr,
                                                     s_meta, s_w, h_a, N);
    layer64_kernel<<<(N + 7) / 8, 512, 0, stream>>>(h_a, wb1, B1, row_ptr,
                                                    s_meta, s_w, h_b, N);
    layer64_kernel<<<(N + 7) / 8, 512, 0, stream>>>(h_b, wb2, B2, row_ptr,
                                                    s_meta, s_w, (float*)d_out, N);
}

// Round 13
// 658.842 us; speedup vs baseline: 1.0858x; 1.0334x over previous
//
#include <hip/hip_runtime.h>
#include <cstdint>

// SplineConv MeshEncoder: 3 layers, K=3 DIM=3 M=27, dims 3->64->64->64.
// R13 = R12 (layer64 unchanged as control: 227us plateau, Phase A-bound) with
// tail work:
//  (1) layer0 dual-edge Phase A: lane halves process edges 2p / 2p+1 of the
//      same node into separate LDS acc copies (no RMW races); iterations per
//      node halve. Phase B sums the copies.
//  (2) build_wb fused to one launch.

typedef __attribute__((ext_vector_type(8))) short short8;
typedef __attribute__((ext_vector_type(4))) float floatx4;

__device__ inline short f2bf(float f) {
    union { float f; unsigned u; } x; x.f = f;
    unsigned r = x.u + 0x7FFF + ((x.u >> 16) & 1);   // round-to-nearest-even
    return (short)(r >> 16);
}

// ---------------- preprocessing (R10-proven) ----------------

__global__ void count_kernel(const int* __restrict__ ei, int* __restrict__ count, int E) {
    int e = blockIdx.x * blockDim.x + threadIdx.x;
    if (e < E) atomicAdd(&count[ei[E + e]], 1);
}

__global__ __launch_bounds__(1024) void scan_tile_kernel(const int* __restrict__ count,
                                                         int* __restrict__ row_ptr,
                                                         int* __restrict__ bsum, int N) {
    __shared__ int wsum[16];
    int tid = threadIdx.x, lane = tid & 63, wid = tid >> 6;
    int i = blockIdx.x * 1024 + tid;
    int v = (i < N) ? count[i] : 0;
    int incl = v;
#pragma unroll
    for (int off = 1; off < 64; off <<= 1) {
        int t = __shfl_up(incl, off, 64);
        if (lane >= off) incl += t;
    }
    if (lane == 63) wsum[wid] = incl;
    __syncthreads();
    if (tid < 16) {
        int w = wsum[tid];
#pragma unroll
        for (int off = 1; off < 16; off <<= 1) {
            int t = __shfl_up(w, off, 16);
            if ((tid & 15) >= off) w += t;
        }
        wsum[tid] = w;
    }
    __syncthreads();
    int waveoff = (wid > 0) ? wsum[wid - 1] : 0;
    if (i < N) row_ptr[i] = waveoff + incl - v;
    if (tid == 1023) bsum[blockIdx.x] = waveoff + incl;
}

__global__ __launch_bounds__(64) void scan_bsum_kernel(const int* __restrict__ bsum,
                                                       int* __restrict__ boff,
                                                       int* __restrict__ tot, int nb) {
    int tid = threadIdx.x;
    int v = (tid < nb) ? bsum[tid] : 0;
    int incl = v;
#pragma unroll
    for (int off = 1; off < 64; off <<= 1) {
        int t = __shfl_up(incl, off, 64);
        if (tid >= off) incl += t;
    }
    boff[tid] = incl - v;
    if (tid == 63) tot[0] = incl;
}

__global__ __launch_bounds__(1024) void scan_add_kernel(int* __restrict__ row_ptr,
                                                        const int* __restrict__ boff,
                                                        const int* __restrict__ tot,
                                                        int* __restrict__ cursor, int N) {
    int i = blockIdx.x * 1024 + threadIdx.x;
    if (i < N) {
        int r = row_ptr[i] + boff[blockIdx.x];
        row_ptr[i] = r;
        cursor[i] = r;
    }
    if (i == 0) row_ptr[N] = tot[0];
}

// Per edge: meta = src | base<<24, weights pre-scaled by 1/deg, scattered to
// dst-sorted position (two float4 stores). kidx = base + {0,1,3,4,9,10,12,13}[c].
__global__ void basis_sort_kernel(const int* __restrict__ ei, const float* __restrict__ attr,
                                  const int* __restrict__ count, int* __restrict__ cursor,
                                  int* __restrict__ s_meta, float* __restrict__ s_w, int E) {
    int e = blockIdx.x * blockDim.x + threadIdx.x;
    if (e >= E) return;
    int src = ei[e];
    int dst = ei[E + e];
    float f[3]; int i0[3];
#pragma unroll
    for (int d = 0; d < 3; d++) {
        float pos = attr[e * 3 + d] * 2.0f;          // K-1 = 2
        float fl = floorf(pos);
        fl = fminf(fmaxf(fl, 0.0f), 1.0f);           // clip to [0, K-2]
        i0[d] = (int)fl;
        f[d] = pos - fl;
    }
    int base = i0[0] + 3 * i0[1] + 9 * i0[2];        // in {0,1,3,4,9,10,12,13}
    float invd = 1.0f / fmaxf((float)count[dst], 1.0f);
    int p = atomicAdd(&cursor[dst], 1);
    s_meta[p] = src | (base << 24);
    float w[8];
#pragma unroll
    for (int c = 0; c < 8; c++) {
        float ww = 1.0f;
#pragma unroll
        for (int d = 0; d < 3; d++) {
            int off = (c >> d) & 1;
            ww *= off ? f[d] : (1.0f - f[d]);
        }
        w[c] = ww * invd;
    }
    floatx4 w03 = {w[0], w[1], w[2], w[3]};
    floatx4 w47 = {w[4], w[5], w[6], w[7]};
    *(floatx4*)(s_w + (size_t)p * 8) = w03;
    *(floatx4*)(s_w + (size_t)p * 8 + 4) = w47;
}

// Pre-swizzle [W(1728,64); Wr(64,64)] into bf16 MFMA B-frag order (R1-proven).
// Fused: one launch builds both layers' wb.
__global__ void build_wb2(const float* __restrict__ Wa, const float* __restrict__ Ra,
                          unsigned short* __restrict__ wba,
                          const float* __restrict__ Wb, const float* __restrict__ Rb,
                          unsigned short* __restrict__ wbb) {
    int idx0 = blockIdx.x * blockDim.x + threadIdx.x;   // [0, 2*4*56*64)
    int half = idx0 / (4 * 56 * 64);
    if (half >= 2) return;
    int idx = idx0 - half * (4 * 56 * 64);
    const float* W = half ? Wb : Wa;
    const float* Wr = half ? Rb : Ra;
    unsigned short* wb = half ? wbb : wba;
    int l = idx & 63;
    int c = (idx >> 6) % 56;
    int t = idx / (56 * 64);
    int q = l >> 4, o = t * 16 + (l & 15);
    short8 out;
#pragma unroll
    for (int j = 0; j < 8; j++) {
        int k = c * 32 + q * 8 + j;
        float v = (k < 1728) ? W[(size_t)k * 64 + o] : Wr[(size_t)(k - 1728) * 64 + o];
        out[j] = f2bf(v);
    }
    *(short8*)(wb + (size_t)idx * 8) = out;
}

// ---------------- layer 0 (CIN=3): dual-edge Phase A ----------------
// Lane halves d=0/1 process edges 2p+d of the SAME node into SEPARATE LDS acc
// copies (no same-address RMW). Iterations per node: ceil(deg/2).
__global__ __launch_bounds__(256) void layer0_kernel(
    const float* __restrict__ x, const float* __restrict__ W0,
    const float* __restrict__ Wr, const float* __restrict__ bias,
    const int* __restrict__ row_ptr, const int* __restrict__ s_meta,
    const float* __restrict__ s_w, float* __restrict__ h_out, int N) {
    constexpr int NPB = 32, KT = 84;
    __shared__ __align__(16) float acc[NPB * 2 * KT];   // 21.5 KB (dual copies)
    int tid = threadIdx.x, lane = tid & 63, wv = tid >> 6;
    int n0 = blockIdx.x * NPB;
    for (int k = tid; k < NPB * 2 * KT; k += 256) acc[k] = 0.0f;
    __syncthreads();

    int d = lane >> 5, hl = lane & 31;
    int c = hl / 3, i = hl - c * 3;
    bool act = (hl < 24);
    int cc = act ? c : 0;
    int coff = (c & 1) + 3 * ((c >> 1) & 1) + 9 * (c >> 2);   // corner offset

    for (int g2 = 0; g2 < 8; g2++) {
        int g = wv * 8 + g2;
        int n = n0 + g;
        if (n >= N) continue;
        if (lane < 3) acc[(g * 2) * KT + 81 + lane] = x[(size_t)n * 3 + lane];  // root
        int rs = row_ptr[n], re = row_ptr[n + 1];
        int npairs = (re - rs + 1) >> 1;
        float* accd = &acc[(g * 2 + d) * KT];
        for (int pb = 0; pb < npairs; pb += 4) {
            int metas[4]; float ws_[4], xs_[4];
#pragma unroll
            for (int j = 0; j < 4; j++) {            // clamp invalid -> rs (valid, w=0)
                int ej = rs + (pb + j) * 2 + d;
                bool v = (pb + j < npairs) && (ej < re);
                int ec = v ? ej : rs;
                metas[j] = s_meta[ec];
                float wv_ = s_w[(size_t)ec * 8 + cc];
                ws_[j] = v ? wv_ : 0.0f;
            }
#pragma unroll
            for (int j = 0; j < 4; j++)
                xs_[j] = x[(size_t)(metas[j] & 0xFFFFFF) * 3 + i];
#pragma unroll
            for (int j = 0; j < 4; j++) {
                int kidx = ((metas[j] >> 24) & 0xF) + coff;
                if (act) accd[kidx * 3 + i] += ws_[j] * xs_[j];
            }
        }
    }
    __syncthreads();

    // Phase B: o = lane, W in 84 registers; sum the dual acc copies.
    int o = lane;
    float wreg[KT];
#pragma unroll
    for (int k = 0; k < KT; k++)
        wreg[k] = (k < 81) ? W0[k * 64 + o] : Wr[(k - 81) * 64 + o];
    float bv = bias[o];
    for (int g = wv; g < NPB; g += 4) {
        int n = n0 + g;
        if (n >= N) break;
        float s = bv;
#pragma unroll
        for (int k4 = 0; k4 < KT; k4 += 4) {
            floatx4 a0 = *(const floatx4*)&acc[(g * 2) * KT + k4];
            floatx4 a1 = *(const floatx4*)&acc[(g * 2 + 1) * KT + k4];
            s += (a0.x + a1.x) * wreg[k4] + (a0.y + a1.y) * wreg[k4 + 1]
               + (a0.z + a1.z) * wreg[k4 + 2] + (a0.w + a1.w) * wreg[k4 + 3];
        }
        h_out[(size_t)n * 64 + o] = fmaxf(s, 0.0f);
    }
}

// ---------------- 64-ch layers (R12, unchanged control) ----------------
__global__ __launch_bounds__(512) void layer64_kernel(
    const float* __restrict__ h_in, const unsigned short* __restrict__ wb,
    const float* __restrict__ bias, const int* __restrict__ row_ptr,
    const int* __restrict__ s_meta, const float* __restrict__ s_w,
    float* __restrict__ h_out, int N) {
    constexpr int NPB = 8;
    constexpr int STR = 1808;            // shorts; dword-stride 904 = even bank spread
    __shared__ __align__(16) unsigned short accb[NPB * STR];   // 28,928 B
    int tid = threadIdx.x, lane = tid & 63;
    int wvu = __builtin_amdgcn_readfirstlane(tid >> 6);   // uniform wave id 0..7
    int n0 = blockIdx.x * NPB;

#define EDGE_FMA(EIDX, XJ) do { \
    const float* wp = s_w + (size_t)(EIDX) * 8; \
    float w0 = wp[0], w1 = wp[1], w2 = wp[2], w3 = wp[3]; \
    float w4 = wp[4], w5 = wp[5], w6 = wp[6], w7 = wp[7]; \
    float xj = (XJ); \
    switch (bases) { \
    case 0:  acc[0]+=w0*xj;  acc[1]+=w1*xj;  acc[3]+=w2*xj;  acc[4]+=w3*xj; \
             acc[9]+=w4*xj;  acc[10]+=w5*xj; acc[12]+=w6*xj; acc[13]+=w7*xj; break; \
    case 1:  acc[1]+=w0*xj;  acc[2]+=w1*xj;  acc[4]+=w2*xj;  acc[5]+=w3*xj; \
             acc[10]+=w4*xj; acc[11]+=w5*xj; acc[13]+=w6*xj; acc[14]+=w7*xj; break; \
    case 3:  acc[3]+=w0*xj;  acc[4]+=w1*xj;  acc[6]+=w2*xj;  acc[7]+=w3*xj; \
             acc[12]+=w4*xj; acc[13]+=w5*xj; acc[15]+=w6*xj; acc[16]+=w7*xj; break; \
    case 4:  acc[4]+=w0*xj;  acc[5]+=w1*xj;  acc[7]+=w2*xj;  acc[8]+=w3*xj; \
             acc[13]+=w4*xj; acc[14]+=w5*xj; acc[16]+=w6*xj; acc[17]+=w7*xj; break; \
    case 9:  acc[9]+=w0*xj;  acc[10]+=w1*xj; acc[12]+=w2*xj; acc[13]+=w3*xj; \
             acc[18]+=w4*xj; acc[19]+=w5*xj; acc[21]+=w6*xj; acc[22]+=w7*xj; break; \
    case 10: acc[10]+=w0*xj; acc[11]+=w1*xj; acc[13]+=w2*xj; acc[14]+=w3*xj; \
             acc[19]+=w4*xj; acc[20]+=w5*xj; acc[22]+=w6*xj; acc[23]+=w7*xj; break; \
    case 12: acc[12]+=w0*xj; acc[13]+=w1*xj; acc[15]+=w2*xj; acc[16]+=w3*xj; \
             acc[21]+=w4*xj; acc[22]+=w5*xj; acc[24]+=w6*xj; acc[25]+=w7*xj; break; \
    default: acc[13]+=w0*xj; acc[14]+=w1*xj; acc[16]+=w2*xj; acc[17]+=w3*xj; \
             acc[22]+=w4*xj; acc[23]+=w5*xj; acc[25]+=w6*xj; acc[26]+=w7*xj; break; } \
} while (0)

#define BATCH(SZ) do { \
    int metas[SZ]; float xjs[SZ]; \
    _Pragma("unroll") for (int j = 0; j < SZ; j++) metas[j] = s_meta[e + j]; \
    _Pragma("unroll") for (int j = 0; j < SZ; j++) \
        xjs[j] = h_in[(size_t)(metas[j] & 0xFFFFFF) * 64 + lane]; \
    _Pragma("unroll") for (int j = 0; j < SZ; j++) { \
        int bases = (metas[j] >> 24) & 0xF; \
        EDGE_FMA(e + j, xjs[j]); \
    } \
    e += SZ; \
} while (0)

    // Phase A (R8-proven): wave wvu owns node row wvu. lane = channel.
    {
        int r = wvu;
        int n = n0 + r;
        unsigned short* arowb = &accb[r * STR];
        if (n >= N) {   // tail hygiene: zero the row so MFMA sees no stale LDS
            for (int k = lane; k < 1792; k += 64) arowb[k] = 0;
        } else {
            float acc[27];
#pragma unroll
            for (int m = 0; m < 27; m++) acc[m] = 0.0f;
            int rs = row_ptr[n], re = row_ptr[n + 1];
            int e = rs;
            while (e + 16 <= re) BATCH(16);
            if (e + 8 <= re) BATCH(8);
            if (e + 4 <= re) BATCH(4);
            for (; e < re; e++) {                     // <=3 remainder
                int meta = s_meta[e];
                float xjr = h_in[(size_t)(meta & 0xFFFFFF) * 64 + lane];
                int bases = (meta >> 24) & 0xF;
                EDGE_FMA(e, xjr);
            }
#pragma unroll
            for (int m = 0; m < 27; m++)
                arowb[m * 64 + lane] = (unsigned short)f2bf(acc[m]);
            arowb[1728 + lane] = (unsigned short)f2bf(h_in[(size_t)n * 64 + lane]);
        }
    }
#undef BATCH
#undef EDGE_FMA
    __syncthreads();

    // Phase B: all 8 waves, 2-way split-K (broadcast A reads, conflict-free).
    {
        int t = wvu & 3;
        int hf = wvu >> 2;
        const unsigned short* ap = accb + (lane & 7) * STR + ((lane >> 4) * 8);
        floatx4 facc = {0.0f, 0.0f, 0.0f, 0.0f};
        const unsigned short* wbp = wb + ((size_t)(t * 56) * 64 + lane) * 8;
#pragma unroll
        for (int ci = 0; ci < 28; ci++) {
            int c = hf * 28 + ci;
            short8 af = *(const short8*)(ap + c * 32);
            short8 bfr = *(const short8*)(wbp + (size_t)c * 64 * 8);
            facc = __builtin_amdgcn_mfma_f32_16x16x32_bf16(af, bfr, facc, 0, 0, 0);
        }
        __syncthreads();               // all MFMA reads of accb complete
        float* pf = (float*)accb;      // 8 waves x 256 floats = 8KB (fits)
#pragma unroll
        for (int r = 0; r < 4; r++) pf[wvu * 256 + r * 64 + lane] = facc[r];
        __syncthreads();
        if (wvu < 4) {
            int o = t * 16 + (lane & 15);
            float bv = bias[o];
#pragma unroll
            for (int r = 0; r < 4; r++) {
                int m = (lane >> 4) * 4 + r;
                if (m < 8) {
                    int n = n0 + m;
                    if (n < N) {
                        float s = pf[t * 256 + r * 64 + lane]
                                + pf[(t + 4) * 256 + r * 64 + lane];
                        h_out[(size_t)n * 64 + o] = fmaxf(s + bv, 0.0f);
                    }
                }
            }
        }
    }
}

extern "C" void kernel_launch(void* const* d_in, const int* in_sizes, int n_in,
                              void* d_out, int out_size, void* d_ws, size_t ws_size,
                              hipStream_t stream) {
    (void)n_in; (void)out_size; (void)ws_size;
    const float* x    = (const float*)d_in[0];
    const int*   ei   = (const int*)d_in[1];
    const float* attr = (const float*)d_in[2];
    const float* W0 = (const float*)d_in[3];
    const float* R0 = (const float*)d_in[4];
    const float* B0 = (const float*)d_in[5];
    const float* W1 = (const float*)d_in[6];
    const float* R1 = (const float*)d_in[7];
    const float* B1 = (const float*)d_in[8];
    const float* W2 = (const float*)d_in[9];
    const float* R2 = (const float*)d_in[10];
    const float* B2 = (const float*)d_in[11];
    const int N = in_sizes[0] / 3;
    const int E = in_sizes[1] / 2;

    char* ws = (char*)d_ws;
    size_t off = 0;
    auto alloc = [&](size_t bytes) {
        size_t cur = off;
        off = (off + bytes + 255) & ~(size_t)255;
        return cur;
    };
    int* row_ptr = (int*)(ws + alloc((size_t)(N + 1) * 4));
    int* count   = (int*)(ws + alloc((size_t)N * 4));
    int* cursor  = (int*)(ws + alloc((size_t)N * 4));
    int* bsum    = (int*)(ws + alloc(64 * 4));
    int* boff    = (int*)(ws + alloc(64 * 4));
    int* tot     = (int*)(ws + alloc(4));
    int* s_meta  = (int*)(ws + alloc((size_t)E * 4));
    float* s_w   = (float*)(ws + alloc((size_t)E * 8 * 4));
    float* h_a   = (float*)(ws + alloc((size_t)N * 64 * 4));
    float* h_b   = (float*)(ws + alloc((size_t)N * 64 * 4));
    unsigned short* wb1 = (unsigned short*)(ws + alloc((size_t)4 * 56 * 64 * 8 * 2));
    unsigned short* wb2 = (unsigned short*)(ws + alloc((size_t)4 * 56 * 64 * 8 * 2));

    int nb = (N + 1023) / 1024;   // 49 <= 64

    hipMemsetAsync(count, 0, (size_t)N * 4, stream);
    count_kernel<<<(E + 255) / 256, 256, 0, stream>>>(ei, count, E);
    scan_tile_kernel<<<nb, 1024, 0, stream>>>(count, row_ptr, bsum, N);
    scan_bsum_kernel<<<1, 64, 0, stream>>>(bsum, boff, tot, nb);
    scan_add_kernel<<<nb, 1024, 0, stream>>>(row_ptr, boff, tot, cursor, N);
    basis_sort_kernel<<<(E + 255) / 256, 256, 0, stream>>>(ei, attr, count, cursor,
                                                           s_meta, s_w, E);
    build_wb2<<<(2 * 4 * 56 * 64 + 255) / 256, 256, 0, stream>>>(W1, R1, wb1,
                                                                 W2, R2, wb2);

    layer0_kernel<<<(N + 31) / 32, 256, 0, stream>>>(x, W0, R0, B0, row_ptr,
                                                     s_meta, s_w, h_a, N);
    layer64_kernel<<<(N + 7) / 8, 512, 0, stream>>>(h_a, wb1, B1, row_ptr,
                                                    s_meta, s_w, h_b, N);
    layer64_kernel<<<(N + 7) / 8, 512, 0, stream>>>(h_b, wb2, B2, row_ptr,
                                                    s_meta, s_w, (float*)d_out, N);
}